// Round 15
// baseline (845.374 us; speedup 1.0000x reference)
//
#include <hip/hip_runtime.h>
#include <hip/hip_bf16.h>
#include <stdint.h>

#define N_NODES 50000
#define N_EDGES 800000
#define N_TILES (N_EDGES / 16)
#define N_NTILES (N_NODES / 16)             // 3125 exactly
#define NB_SCAN ((N_NODES + 1023) / 1024)   // 49

typedef unsigned int uint32;
typedef __fp16   fp16x2 __attribute__((ext_vector_type(2)));
typedef _Float16 half8v __attribute__((ext_vector_type(8)));
typedef float    f32x4  __attribute__((ext_vector_type(4)));
typedef uint32   u32x2  __attribute__((ext_vector_type(2)));
typedef uint32   u32x4  __attribute__((ext_vector_type(4)));

union H2U { uint32 u; fp16x2 h; };
union H8U { u32x4 u; half8v h; };

__device__ __forceinline__ uint32 pk16(float lo, float hi) {
    H2U z; z.h = __builtin_amdgcn_cvt_pkrtz(lo, hi); return z.u;
}
__device__ __forceinline__ float h16lo(uint32 u) { H2U z; z.u = u; return (float)z.h[0]; }
__device__ __forceinline__ float h16hi(uint32 u) { H2U z; z.u = u; return (float)z.h[1]; }
// silu via v_rcp_f32 (avoids IEEE division expansion; err ~2^-22 << f16 2^-11)
__device__ __forceinline__ float silu(float v) {
    return v * __builtin_amdgcn_rcpf(1.0f + __expf(-v));
}

// ---------- Kernel 0: zero aggregation buffers ------------------------------
__global__ __launch_bounds__(256) void zero_ws(float* __restrict__ p, int n) {
    int i = blockIdx.x * 256 + threadIdx.x;
    int stride = gridDim.x * 256;
    for (; i < n; i += stride) p[i] = 0.0f;
}

// ---------- Kernel 0b: ALL weight fragments (merged prep, 1 launch) ---------
__global__ __launch_bounds__(256) void prep_all(
    const float* __restrict__ W2, const float* __restrict__ Wc1,
    const float* __restrict__ W1, const float* __restrict__ b1,
    const float* __restrict__ Wn1, const float* __restrict__ Wn2,
    uint32* __restrict__ W2A, uint32* __restrict__ WC1A, uint32* __restrict__ W1TF,
    uint32* __restrict__ W1A, uint32* __restrict__ W1B,
    uint32* __restrict__ WN1A, uint32* __restrict__ WN2A)
{
    int i = blockIdx.x * 256 + threadIdx.x;
    if (i >= 16384) return;
    const int p = i & 3, l = (i >> 2) & 63;
    if (i < 8192) {                          // ot 0..7, kb 0..3 (K=128, O=128)
        const int f = i >> 8, ot = f >> 2, kb = f & 3;
        const int k0 = kb * 32 + (l >> 4) * 8 + 2 * p;
        const int o  = (l & 15) + ot * 16;
        W2A[i]  = pk16(W2[(size_t)k0 * 128 + o],  W2[(size_t)(k0 + 1) * 128 + o]);
        WC1A[i] = pk16(Wc1[(size_t)k0 * 128 + o], Wc1[(size_t)(k0 + 1) * 128 + o]);
        W1A[i]  = pk16(W1[(size_t)k0 * 128 + o],         W1[(size_t)(k0 + 1) * 128 + o]);
        W1B[i]  = pk16(W1[(size_t)(128 + k0) * 128 + o], W1[(size_t)(129 + k0) * 128 + o]);
        WN2A[i] = pk16(Wn2[(size_t)k0 * 128 + o],        Wn2[(size_t)(k0 + 1) * 128 + o]);
    }
    {                                        // WN1A: ot 0..7, kb 0..7 (K=256)
        const int f = i >> 8, ot = f >> 3, kb = f & 7;
        const int k0 = kb * 32 + (l >> 4) * 8 + 2 * p;
        const int o  = (l & 15) + ot * 16;
        WN1A[i] = pk16(Wn1[(size_t)k0 * 128 + o], Wn1[(size_t)(k0 + 1) * 128 + o]);
    }
    if (i < 5 * 64) {                        // W1TF: packed tail rows + b1
        const int row = i >> 6, pp = i & 63;
        if (row < 4)
            W1TF[i] = pk16(W1[(size_t)(256 + row) * 128 + 2 * pp],
                           W1[(size_t)(256 + row) * 128 + 2 * pp + 1]);
        else
            W1TF[i] = pk16(b1[2 * pp], b1[2 * pp + 1]);
    }
}

// ---------- Sort-by-dst infrastructure --------------------------------------
__global__ __launch_bounds__(256) void hist_deg(const int* __restrict__ ei,
                                                uint32* __restrict__ deg) {
    int i = blockIdx.x * 256 + threadIdx.x;
    if (i < N_EDGES) atomicAdd(&deg[ei[N_EDGES + i]], 1u);
}

__global__ __launch_bounds__(1024) void scan_local(const uint32* __restrict__ deg,
                                                   uint32* __restrict__ cursor,
                                                   uint32* __restrict__ bsum) {
    __shared__ uint32 wtot[16];
    __shared__ uint32 woff[16];
    const int tid = threadIdx.x;
    const int lane = tid & 63;
    const int wid = tid >> 6;
    const int i = blockIdx.x * 1024 + tid;
    const uint32 v = (i < N_NODES) ? deg[i] : 0u;
    uint32 x = v;
#pragma unroll
    for (int off = 1; off < 64; off <<= 1) {
        uint32 y = __shfl_up(x, off);
        if (lane >= off) x += y;
    }
    if (lane == 63) wtot[wid] = x;
    __syncthreads();
    if (wid == 0) {
        const uint32 wv = (lane < 16) ? wtot[lane] : 0u;
        uint32 wx = wv;
#pragma unroll
        for (int off = 1; off < 16; off <<= 1) {
            uint32 wy = __shfl_up(wx, off);
            if (lane >= off) wx += wy;
        }
        if (lane < 16) woff[lane] = wx - wv;
    }
    __syncthreads();
    if (i < N_NODES) cursor[i] = woff[wid] + x - v;   // block-local exclusive
    if (tid == 1023) bsum[blockIdx.x] = woff[15] + wtot[15];
}

// scan_add with inline top-prefix: each 256-block spans exactly one 1024-group
// (256-aligned), so it needs ONE prefix value = sum(bsum[0..g-1]), g<=48<64.
// Wave 0 reduces it; no separate single-block scan_top launch (GPU bubble).
__global__ __launch_bounds__(256) void scan_add(uint32* __restrict__ cursor,
                                                const uint32* __restrict__ bsum) {
    __shared__ uint32 sOff;
    const int tid = threadIdx.x;
    const int g = (blockIdx.x * 256) >> 10;
    if (tid < 64) {
        uint32 v = (tid < g) ? bsum[tid] : 0u;
#pragma unroll
        for (int off = 32; off; off >>= 1) v += __shfl_down(v, off);
        if (tid == 0) sOff = v;
    }
    __syncthreads();
    const int i = blockIdx.x * 256 + tid;
    if (i < N_NODES) cursor[i] += sOff;
}

__global__ __launch_bounds__(256) void scatter_perm(const int* __restrict__ ei,
                                                    uint32* __restrict__ cursor,
                                                    uint32* __restrict__ perm) {
    int i = blockIdx.x * 256 + threadIdx.x;
    if (i < N_EDGES) {
        const int d = ei[N_EDGES + i];
        const uint32 pos = atomicAdd(&cursor[d], 1u);
        perm[pos] = (uint32)i;
    }
}

// ---------- Kernel 1: pre-projection via MFMA (R9 proven version) -----------
__global__ __launch_bounds__(256, 4) void pre_proj(
    const float* __restrict__ h,
    const uint32* __restrict__ W1A, const uint32* __restrict__ W1B,
    uint32* __restrict__ A, uint32* __restrict__ B)
{
    __shared__ uint32 sWA[8192];
    const int tid = threadIdx.x;
#pragma unroll
    for (int i = tid; i < 2048; i += 256)
        ((u32x4*)sWA)[i] = ((const u32x4*)W1A)[i];
    __syncthreads();

    const int lane = tid & 63, wv = tid >> 6;
    const int quad = lane >> 4, nown = lane & 15;
    const int t = blockIdx.x * 4 + wv;
    if (t >= N_NTILES) return;
    const int n0 = t * 16;

    const float* hrow = h + (size_t)(n0 + nown) * 128 + quad * 8;
    H8U hf[4];
#pragma unroll
    for (int kb = 0; kb < 4; ++kb) {
        const f32x4 a = *(const f32x4*)(hrow + kb * 32);
        const f32x4 b = *(const f32x4*)(hrow + kb * 32 + 4);
        hf[kb].u[0] = pk16(a[0], a[1]); hf[kb].u[1] = pk16(a[2], a[3]);
        hf[kb].u[2] = pk16(b[0], b[1]); hf[kb].u[3] = pk16(b[2], b[3]);
    }

    const size_t obase = (size_t)(n0 + nown) * 64;
#pragma unroll
    for (int ot = 0; ot < 8; ++ot) {
        f32x4 acc = {0.f, 0.f, 0.f, 0.f};
#pragma unroll
        for (int kb = 0; kb < 4; ++kb) {
            H8U w; w.u = *(const u32x4*)&sWA[((ot * 4 + kb) * 64 + lane) * 4];
            acc = __builtin_amdgcn_mfma_f32_16x16x32_f16(w.h, hf[kb].h, acc, 0, 0, 0);
        }
        A[obase + 8 * ot + 2 * quad]     = pk16(acc[0], acc[1]);
        A[obase + 8 * ot + 2 * quad + 1] = pk16(acc[2], acc[3]);
    }
#pragma unroll
    for (int ot = 0; ot < 8; ++ot) {
        f32x4 acc = {0.f, 0.f, 0.f, 0.f};
#pragma unroll
        for (int kb = 0; kb < 4; ++kb) {
            H8U w; w.u = *(const u32x4*)(W1B + (size_t)((ot * 4 + kb) * 64 + lane) * 4);
            acc = __builtin_amdgcn_mfma_f32_16x16x32_f16(w.h, hf[kb].h, acc, 0, 0, 0);
        }
        B[obase + 8 * ot + 2 * quad]     = pk16(acc[0], acc[1]);
        B[obase + 8 * ot + 2 * quad + 1] = pk16(acc[2], acc[3]);
    }
}

// ---------- Kernel 2: MFMA edge kernel (R13 body, bounds (256,3)) -----------
// R14/R15: (256,4)->(256,3). VGPR_Count pinned at exactly the 128 cap since
// R8 -- allocator starved. Residency is LDS-capped at 3 blocks/CU (50176 B)
// regardless, so raising the reg cap to 170 costs zero occupancy and can
// only improve scheduling (deeper load hoisting, less remat).
#define EWAVES 4
__global__ __launch_bounds__(256, 3) void edge_mfma(
    const int* __restrict__ ei, const float* __restrict__ x,
    const float* __restrict__ eattr,
    const float* __restrict__ b2, const float* __restrict__ bc1,
    const float* __restrict__ Wc2, const float* __restrict__ bc2,
    const uint32* __restrict__ W2A, const uint32* __restrict__ WC1A,
    const uint32* __restrict__ W1TF,
    const uint32* __restrict__ Apk, const uint32* __restrict__ Bpk,
    const uint32* __restrict__ perm,
    float* __restrict__ agg_msg, float* __restrict__ agg_coord)
{
    __shared__ uint32 sM2[EWAVES * 16 * 68];   // per-wave m2 transpose staging
    __shared__ uint32 sW2[8192];               // W2A weight fragments (32 KB)

    const int tid   = threadIdx.x;
    const int lane  = tid & 63;
    const int wv    = tid >> 6;
    const int quad  = lane >> 4;
    const int e_own = lane & 15;
    const int swb   = wv * (16 * 68);
    const float bc2f = bc2[0];

    // stage W2A -> LDS, barrier before any early return
#pragma unroll
    for (int i = tid; i < 2048; i += 256)
        ((u32x4*)sW2)[i] = ((const u32x4*)W2A)[i];
    __syncthreads();

    const int wave = blockIdx.x * EWAVES + wv;
    const int nw   = gridDim.x * EWAVES;

    // contiguous, balanced tile range
    const int q  = N_TILES / nw, r = N_TILES % nw;
    const int t0 = wave * q + (wave < r ? wave : r);
    const int t1 = t0 + q + (wave < r ? 1 : 0);
    if (t0 >= t1) return;

    // pipeline registers ("n" = tile whose m1 is being prepared)
    int nsrc, ndst; float nrx, nry, nrz, ndsq, ne0, ne1, ne2;
    u32x4 av[4], bv[4];
    half8v m1h[4];

    auto load_tile_e = [&](int eidx) {
        nsrc = ei[eidx];
        ndst = ei[N_EDGES + eidx];
        nrx = x[nsrc * 3 + 0] - x[ndst * 3 + 0];
        nry = x[nsrc * 3 + 1] - x[ndst * 3 + 1];
        nrz = x[nsrc * 3 + 2] - x[ndst * 3 + 2];
        ndsq = nrx * nrx + nry * nry + nrz * nrz;
        ne0 = eattr[(size_t)eidx * 3 + 0];
        ne1 = eattr[(size_t)eidx * 3 + 1];
        ne2 = eattr[(size_t)eidx * 3 + 2];
#pragma unroll
        for (int kb = 0; kb < 4; ++kb) {
            av[kb] = *(const u32x4*)&Apk[(size_t)nsrc * 64 + kb * 16 + quad * 4];
            bv[kb] = *(const u32x4*)&Bpk[(size_t)ndst * 64 + kb * 16 + quad * 4];
        }
    };

    auto compute_m1 = [&]() {
        const _Float16 s0 = (_Float16)ne0, s1 = (_Float16)ne1;
        const _Float16 s2 = (_Float16)ne2, sd = (_Float16)ndsq;
#pragma unroll
        for (int kb = 0; kb < 4; ++kb) {
            const int base = kb * 16 + quad * 4;
            H8U a, b, w0, w1, w2, w3, w4;
            a.u  = av[kb]; b.u = bv[kb];
            w0.u = *(const u32x4*)&W1TF[0 * 64 + base];
            w1.u = *(const u32x4*)&W1TF[1 * 64 + base];
            w2.u = *(const u32x4*)&W1TF[2 * 64 + base];
            w3.u = *(const u32x4*)&W1TF[3 * 64 + base];
            w4.u = *(const u32x4*)&W1TF[4 * 64 + base];
            half8v s = a.h + b.h + w4.h;
            s += w0.h * s0;
            s += w1.h * s1;
            s += w2.h * s2;
            s += w3.h * sd;
            half8v m;
#pragma unroll
            for (int j = 0; j < 8; ++j) m[j] = (_Float16)silu((float)s[j]);
            m1h[kb] = m;
        }
    };

    // run-merge state
    int   curDst = -1;
    bool  firstRun = true;
    float aLo = 0.f, aHi = 0.f, cX = 0.f, cY = 0.f, cZ = 0.f;

    auto flush = [&](bool atom) {
        float* row = &agg_msg[(size_t)curDst * 128 + 2 * lane];
        const float cc = (lane == 0) ? cX : ((lane == 1) ? cY : cZ);
        if (atom) {
            atomicAdd(row,     aLo);
            atomicAdd(row + 1, aHi);
            if (lane < 3) atomicAdd(&agg_coord[curDst * 3 + lane], cc);
        } else {
            *(float2*)row = make_float2(aLo, aHi);
            if (lane < 3) agg_coord[curDst * 3 + lane] = cc;
        }
    };

    // perm prefetched one tile ahead (breaks the perm->ei->gather chain)
    int pe = (int)perm[t0 * 16 + e_own];
    {
        const int ec = pe;
        if (t0 + 1 < t1) pe = (int)perm[(t0 + 1) * 16 + e_own];
        load_tile_e(ec);
    }
    compute_m1();

    int t = t0;
    while (t < t1) {
        const int   dst_own = ndst;
        const float rxo = nrx, ryo = nry, rzo = nrz;
        const int   tn = t + 1;
        const bool  more = (tn < t1);
        if (more) {                          // gathers issue BEFORE stores below
            const int ec = pe;
            if (tn + 1 < t1) pe = (int)perm[(tn + 1) * 16 + e_own];
            load_tile_e(ec);
        }

        // ---- matmul 1: D1[o][e] = sum_k W2[k][o] * m1[e][k]  (weights: LDS)
        f32x4 acc[8];
#pragma unroll
        for (int ot = 0; ot < 8; ++ot) acc[ot] = 0.0f;
#pragma unroll 2
        for (int ot = 0; ot < 8; ++ot) {
#pragma unroll
            for (int kb = 0; kb < 4; ++kb) {
                H8U w; w.u = *(const u32x4*)&sW2[((ot * 4 + kb) * 64 + lane) * 4];
                acc[ot] = __builtin_amdgcn_mfma_f32_16x16x32_f16(w.h, m1h[kb], acc[ot], 0, 0, 0);
            }
        }

        // ---- epilogue 1: m2 = silu(D1+b2) -> LDS transpose stage -----------
#pragma unroll
        for (int ot = 0; ot < 8; ++ot) {
            const f32x4 bb = *(const f32x4*)(b2 + 16 * ot + 4 * quad);
            const float m0  = silu(acc[ot][0] + bb[0]);
            const float m1_ = silu(acc[ot][1] + bb[1]);
            const float m2_ = silu(acc[ot][2] + bb[2]);
            const float m3_ = silu(acc[ot][3] + bb[3]);
            u32x2 pair;
            pair[0] = pk16(m0, m1_);
            pair[1] = pk16(m2_, m3_);
            *(u32x2*)&sM2[swb + e_own * 68 + 8 * ot + 2 * quad] = pair;
        }

        // ---- B-frags of m2^T ----------------------------------------------
        H8U m2f[4];
#pragma unroll
        for (int kb = 0; kb < 4; ++kb)
            m2f[kb].u = *(const u32x4*)&sM2[swb + e_own * 68 + kb * 16 + quad * 4];

        // ---- matmul 2 + epilogue 2 fused per ot (one f32x4 acc live) -------
        float partial = 0.0f;
#pragma unroll
        for (int ot = 0; ot < 8; ++ot) {
            f32x4 a2 = {0.f, 0.f, 0.f, 0.f};
#pragma unroll
            for (int kb = 0; kb < 4; ++kb) {
                H8U w; w.u = *(const u32x4*)(WC1A + (size_t)((ot * 4 + kb) * 64 + lane) * 4);
                a2 = __builtin_amdgcn_mfma_f32_16x16x32_f16(w.h, m2f[kb].h, a2, 0, 0, 0);
            }
            const f32x4 bb = *(const f32x4*)(bc1 + 16 * ot + 4 * quad);
            const f32x4 wc = *(const f32x4*)(Wc2 + 16 * ot + 4 * quad);
#pragma unroll
            for (int rr = 0; rr < 4; ++rr)
                partial += silu(a2[rr] + bb[rr]) * wc[rr];
        }
        partial += __shfl_xor(partial, 16);
        partial += __shfl_xor(partial, 32);
        const float cw = partial + bc2f;     // full sum, all lanes, edge e_own
        const float pX = rxo * cw, pY = ryo * cw, pZ = rzo * cw;

        // ---- preload transposed m2 rows (independent, pipelined ds_reads;
        //      latency overlaps the shfl scan chain below) ------------------
        uint32 vreg[16];
#pragma unroll
        for (int e = 0; e < 16; ++e)
            vreg[e] = sM2[swb + e * 68 + lane];

        // ---- coord prefix scan across the 16 edges (per-quad, replicated) --
        float sx = pX, sy = pY, sz = pZ;
#pragma unroll
        for (int off = 1; off < 16; off <<= 1) {
            const float tx = __shfl_up(sx, off, 16);
            const float ty = __shfl_up(sy, off, 16);
            const float tz = __shfl_up(sz, off, 16);
            if (e_own >= off) { sx += tx; sy += ty; sz += tz; }
        }

        // ---- run boundary ballot ------------------------------------------
        const int pd = __shfl(dst_own, (e_own + 15) & 15, 16);
        const bool bnd = (e_own == 0) ? (dst_own != curDst) : (dst_own != pd);
        const uint32 m = (uint32)__ballot(bnd) & 0xffffu;

        // ---- run-merged aggregation (register-resident, predicated) --------
        int pos = 0;
        while (pos < 16) {
            if (m & (1u << pos)) {           // boundary: flush previous run
                if (curDst >= 0) { flush(firstRun); firstRun = false; }
                curDst = __shfl(dst_own, pos, 16);
                aLo = 0.f; aHi = 0.f; cX = 0.f; cY = 0.f; cZ = 0.f;
            }
            const uint32 rest = (pos < 15) ? ((m >> (pos + 1)) << (pos + 1)) : 0u;
            const int nxt = rest ? (__ffs(rest) - 1) : 16;
#pragma unroll
            for (int e = 0; e < 16; ++e) {   // compile-time index (rule #20)
                if (e >= pos && e < nxt) {
                    aLo += h16lo(vreg[e]);
                    aHi += h16hi(vreg[e]);
                }
            }
            const float ex = __shfl(sx, nxt - 1, 16);
            const float ey = __shfl(sy, nxt - 1, 16);
            const float ez = __shfl(sz, nxt - 1, 16);
            float bx = 0.f, by = 0.f, bz = 0.f;
            if (pos > 0) {
                bx = __shfl(sx, pos - 1, 16);
                by = __shfl(sy, pos - 1, 16);
                bz = __shfl(sz, pos - 1, 16);
            }
            cX += ex - bx; cY += ey - by; cZ += ez - bz;
            pos = nxt;
        }

        if (more) compute_m1();              // waits on gathers (older than stores)
        t = tn;
    }
    if (curDst >= 0) flush(true);            // last run may span into next wave
}

// ---------- Kernel 3: node MLP + layernorm + x_out (R9 proven version) ------
__global__ __launch_bounds__(256, 4) void node_kernel(
    const float* __restrict__ h, const float* __restrict__ x,
    const uint32* __restrict__ WN1A, const uint32* __restrict__ WN2A,
    const float* __restrict__ bn1, const float* __restrict__ bn2,
    const float* __restrict__ gamma, const float* __restrict__ beta,
    const float* __restrict__ agg_msg, const float* __restrict__ agg_coord,
    const uint32* __restrict__ deg, float* __restrict__ out)
{
    __shared__ uint32 sW1[8192];             // h-half of Wn1 frags (32 KB)
    __shared__ uint32 sZ[4 * 16 * 68];       // per-wave z transpose staging

    const int tid = threadIdx.x;
    // compact stage: sW1 frag (ot,kb) for kb 0..3  <- WN1A frag ot*8+kb
#pragma unroll
    for (int i = tid; i < 2048; i += 256) {
        const int fc = i >> 6, w = i & 63;   // u32x4 units: 64 vec4 per frag
        const int ot = fc >> 2, kb = fc & 3;
        ((u32x4*)sW1)[i] = ((const u32x4*)WN1A)[(ot * 8 + kb) * 64 + w];
    }
    __syncthreads();

    const int lane = tid & 63, wv = tid >> 6;
    const int quad = lane >> 4, nown = lane & 15;
    const int swb = wv * (16 * 68);

    for (int t = blockIdx.x * 4 + wv; t < N_NTILES; t += gridDim.x * 4) {
        const int n0 = t * 16;
        const int n  = n0 + nown;

        // ---- load h and agg_msg as f16 B-fragments -------------------------
        const float* hrow = h       + (size_t)n * 128 + quad * 8;
        const float* mrow = agg_msg + (size_t)n * 128 + quad * 8;
        H8U hf[4], mf[4];
#pragma unroll
        for (int kb = 0; kb < 4; ++kb) {
            const f32x4 a = *(const f32x4*)(hrow + kb * 32);
            const f32x4 b = *(const f32x4*)(hrow + kb * 32 + 4);
            hf[kb].u[0] = pk16(a[0], a[1]); hf[kb].u[1] = pk16(a[2], a[3]);
            hf[kb].u[2] = pk16(b[0], b[1]); hf[kb].u[3] = pk16(b[2], b[3]);
            const f32x4 c = *(const f32x4*)(mrow + kb * 32);
            const f32x4 d = *(const f32x4*)(mrow + kb * 32 + 4);
            mf[kb].u[0] = pk16(c[0], c[1]); mf[kb].u[1] = pk16(c[2], c[3]);
            mf[kb].u[2] = pk16(d[0], d[1]); mf[kb].u[3] = pk16(d[2], d[3]);
        }

        // ---- mm1: y1 = [h, agg]@Wn1 ; z = silu(y1+bn1) -> LDS transpose ----
#pragma unroll
        for (int ot = 0; ot < 8; ++ot) {
            f32x4 acc = {0.f, 0.f, 0.f, 0.f};
#pragma unroll
            for (int kb = 0; kb < 4; ++kb) {
                H8U w; w.u = *(const u32x4*)&sW1[((ot * 4 + kb) * 64 + lane) * 4];
                acc = __builtin_amdgcn_mfma_f32_16x16x32_f16(w.h, hf[kb].h, acc, 0, 0, 0);
            }
#pragma unroll
            for (int kb = 0; kb < 4; ++kb) {
                H8U w; w.u = *(const u32x4*)(WN1A + (size_t)((ot * 8 + 4 + kb) * 64 + lane) * 4);
                acc = __builtin_amdgcn_mfma_f32_16x16x32_f16(w.h, mf[kb].h, acc, 0, 0, 0);
            }
            const f32x4 bb = *(const f32x4*)(bn1 + 16 * ot + 4 * quad);
            u32x2 pair;
            pair[0] = pk16(silu(acc[0] + bb[0]), silu(acc[1] + bb[1]));
            pair[1] = pk16(silu(acc[2] + bb[2]), silu(acc[3] + bb[3]));
            *(u32x2*)&sZ[swb + nown * 68 + 8 * ot + 2 * quad] = pair;
        }

        // ---- z B-frags -----------------------------------------------------
        H8U zf[4];
#pragma unroll
        for (int kb = 0; kb < 4; ++kb)
            zf[kb].u = *(const u32x4*)&sZ[swb + nown * 68 + kb * 16 + quad * 4];

        // ---- mm2: u = z@Wn2 + bn2 ; y = h + u ; LN stats -------------------
        f32x4 y[8];
        float s1 = 0.f, s2 = 0.f;
#pragma unroll
        for (int ot = 0; ot < 8; ++ot) {
            f32x4 acc = {0.f, 0.f, 0.f, 0.f};
#pragma unroll
            for (int kb = 0; kb < 4; ++kb) {
                H8U w; w.u = *(const u32x4*)(WN2A + (size_t)((ot * 4 + kb) * 64 + lane) * 4);
                acc = __builtin_amdgcn_mfma_f32_16x16x32_f16(w.h, zf[kb].h, acc, 0, 0, 0);
            }
            const f32x4 bb = *(const f32x4*)(bn2 + 16 * ot + 4 * quad);
            const f32x4 hv = *(const f32x4*)(h + (size_t)n * 128 + 16 * ot + 4 * quad);
#pragma unroll
            for (int rr = 0; rr < 4; ++rr) {
                const float v = acc[rr] + bb[rr] + hv[rr];
                y[ot][rr] = v; s1 += v; s2 += v * v;
            }
        }
        s1 += __shfl_xor(s1, 16); s1 += __shfl_xor(s1, 32);
        s2 += __shfl_xor(s2, 16); s2 += __shfl_xor(s2, 32);
        const float mu  = s1 * (1.0f / 128.0f);
        const float var = s2 * (1.0f / 128.0f) - mu * mu;
        const float rs  = rsqrtf(var + 1e-5f);

#pragma unroll
        for (int ot = 0; ot < 8; ++ot) {
            const f32x4 gv = *(const f32x4*)(gamma + 16 * ot + 4 * quad);
            const f32x4 bv = *(const f32x4*)(beta + 16 * ot + 4 * quad);
            f32x4 o4;
#pragma unroll
            for (int rr = 0; rr < 4; ++rr)
                o4[rr] = (y[ot][rr] - mu) * rs * gv[rr] + bv[rr];
            *(f32x4*)(out + (size_t)n * 128 + 16 * ot + 4 * quad) = o4;
        }

        // ---- x_out ---------------------------------------------------------
        if (lane < 48) {
            const int nn = n0 + lane / 3, c = lane - (lane / 3) * 3;
            const float cdeg = fmaxf((float)deg[nn], 1.0f);
            out[(size_t)N_NODES * 128 + (size_t)nn * 3 + c] =
                x[nn * 3 + c] + agg_coord[nn * 3 + c] / cdeg;
        }
    }
}

extern "C" void kernel_launch(void* const* d_in, const int* in_sizes, int n_in,
                              void* d_out, int out_size, void* d_ws, size_t ws_size,
                              hipStream_t stream)
{
    const float* h     = (const float*)d_in[0];
    const float* x     = (const float*)d_in[1];
    const int*   ei    = (const int*)d_in[2];
    const float* eattr = (const float*)d_in[3];
    const float* W1    = (const float*)d_in[4];
    const float* b1    = (const float*)d_in[5];
    const float* W2    = (const float*)d_in[6];
    const float* b2    = (const float*)d_in[7];
    const float* Wc1   = (const float*)d_in[8];
    const float* bc1   = (const float*)d_in[9];
    const float* Wc2   = (const float*)d_in[10];
    const float* bc2   = (const float*)d_in[11];
    const float* Wn1   = (const float*)d_in[12];
    const float* bn1   = (const float*)d_in[13];
    const float* Wn2   = (const float*)d_in[14];
    const float* bn2   = (const float*)d_in[15];
    const float* gamma = (const float*)d_in[16];
    const float* beta  = (const float*)d_in[17];

    // ws layout (~57.5 MB)
    uint32* A        = (uint32*)d_ws;                      // N*64 u32 (f16x2)
    uint32* B        = A + (size_t)N_NODES * 64;           // N*64 u32
    float* agg_msg   = (float*)(B + (size_t)N_NODES * 64); // N*128 f32 (zeroed)
    float* agg_coord = agg_msg + (size_t)N_NODES * 128;    // N*3 (zeroed)
    uint32* deg      = (uint32*)(agg_coord + (size_t)N_NODES * 3); // N (zeroed)
    uint32* cursor   = deg + N_NODES;                      // N
    uint32* perm     = cursor + N_NODES;                   // E
    uint32* W2A      = perm + N_EDGES;                     // 8192 u32
    uint32* WC1A     = W2A + 8192;                         // 8192 u32
    uint32* W1TF     = WC1A + 8192;                        // 320 u32
    uint32* bsum     = W1TF + 320;                         // 64 u32
    uint32* W1A      = bsum + 64;                          // 8192 u32
    uint32* W1B      = W1A + 8192;                         // 8192 u32
    uint32* WN1A     = W1B + 8192;                         // 16384 u32
    uint32* WN2A     = WN1A + 16384;                       // 8192 u32

    const int zero_elems = N_NODES * 128 + N_NODES * 3 + N_NODES;  // msg+coord+deg
    zero_ws<<<512, 256, 0, stream>>>(agg_msg, zero_elems);
    prep_all<<<64, 256, 0, stream>>>(W2, Wc1, W1, b1, Wn1, Wn2,
                                     W2A, WC1A, W1TF, W1A, W1B, WN1A, WN2A);
    hist_deg<<<3125, 256, 0, stream>>>(ei, deg);
    scan_local<<<NB_SCAN, 1024, 0, stream>>>(deg, cursor, bsum);
    scan_add<<<196, 256, 0, stream>>>(cursor, bsum);
    scatter_perm<<<3125, 256, 0, stream>>>(ei, cursor, perm);
    pre_proj<<<782, 256, 0, stream>>>(h, W1A, W1B, A, B);
    edge_mfma<<<768, 256, 0, stream>>>(ei, x, eattr, b2, bc1, Wc2, bc2,
                                       W2A, WC1A, W1TF, A, B, perm,
                                       agg_msg, agg_coord);
    node_kernel<<<768, 256, 0, stream>>>(h, x, WN1A, WN2A, bn1, bn2,
                                         gamma, beta, agg_msg, agg_coord,
                                         deg, (float*)d_out);
}

// Round 16
// 704.350 us; speedup vs baseline: 1.2002x; 1.2002x over previous
//
#include <hip/hip_runtime.h>
#include <hip/hip_bf16.h>
#include <stdint.h>

#define N_NODES 50000
#define N_EDGES 800000
#define N_TILES (N_EDGES / 16)
#define N_NTILES (N_NODES / 16)             // 3125 exactly
#define NB_SCAN ((N_NODES + 1023) / 1024)   // 49

typedef unsigned int uint32;
typedef __fp16   fp16x2 __attribute__((ext_vector_type(2)));
typedef _Float16 half8v __attribute__((ext_vector_type(8)));
typedef float    f32x4  __attribute__((ext_vector_type(4)));
typedef uint32   u32x2  __attribute__((ext_vector_type(2)));
typedef uint32   u32x4  __attribute__((ext_vector_type(4)));

union H2U { uint32 u; fp16x2 h; };
union H8U { u32x4 u; half8v h; };

__device__ __forceinline__ uint32 pk16(float lo, float hi) {
    H2U z; z.h = __builtin_amdgcn_cvt_pkrtz(lo, hi); return z.u;
}
__device__ __forceinline__ float h16lo(uint32 u) { H2U z; z.u = u; return (float)z.h[0]; }
__device__ __forceinline__ float h16hi(uint32 u) { H2U z; z.u = u; return (float)z.h[1]; }
// silu via v_rcp_f32 (avoids IEEE division expansion; err ~2^-22 << f16 2^-11)
__device__ __forceinline__ float silu(float v) {
    return v * __builtin_amdgcn_rcpf(1.0f + __expf(-v));
}

// ---------- Kernel 0: zero aggregation buffers ------------------------------
__global__ __launch_bounds__(256) void zero_ws(float* __restrict__ p, int n) {
    int i = blockIdx.x * 256 + threadIdx.x;
    int stride = gridDim.x * 256;
    for (; i < n; i += stride) p[i] = 0.0f;
}

// ---------- Kernel 0b: weight fragments (f16x2) in ws -----------------------
__global__ __launch_bounds__(256) void prep_frags(
    const float* __restrict__ W2, const float* __restrict__ Wc1,
    const float* __restrict__ W1, const float* __restrict__ b1,
    uint32* __restrict__ W2A, uint32* __restrict__ WC1A, uint32* __restrict__ W1TF)
{
    int i = blockIdx.x * 256 + threadIdx.x;
    if (i < 8192) {
        const int p = i & 3, l = (i >> 2) & 63, f = i >> 8;
        const int ot = f >> 2, kb = f & 3;
        const int k0 = kb * 32 + (l >> 4) * 8 + 2 * p;
        const int o  = (l & 15) + ot * 16;
        W2A[i]  = pk16(W2[(size_t)k0 * 128 + o],  W2[(size_t)(k0 + 1) * 128 + o]);
        WC1A[i] = pk16(Wc1[(size_t)k0 * 128 + o], Wc1[(size_t)(k0 + 1) * 128 + o]);
    }
    if (i < 5 * 64) {
        const int row = i >> 6, p = i & 63;
        if (row < 4)
            W1TF[i] = pk16(W1[(size_t)(256 + row) * 128 + 2 * p],
                           W1[(size_t)(256 + row) * 128 + 2 * p + 1]);
        else
            W1TF[i] = pk16(b1[2 * p], b1[2 * p + 1]);
    }
}

// ---------- Kernel 0c: node-side weight fragments ---------------------------
__global__ __launch_bounds__(256) void prep_frags2(
    const float* __restrict__ W1, const float* __restrict__ Wn1,
    const float* __restrict__ Wn2,
    uint32* __restrict__ W1A, uint32* __restrict__ W1B,
    uint32* __restrict__ WN1A, uint32* __restrict__ WN2A)
{
    int i = blockIdx.x * 256 + threadIdx.x;
    if (i >= 16384) return;
    const int p = i & 3, l = (i >> 2) & 63;
    if (i < 8192) {                          // ot 0..7, kb 0..3 (K=128, O=128)
        const int f = i >> 8, ot = f >> 2, kb = f & 3;
        const int k0 = kb * 32 + (l >> 4) * 8 + 2 * p;
        const int o  = (l & 15) + ot * 16;
        W1A[i]  = pk16(W1[(size_t)k0 * 128 + o],         W1[(size_t)(k0 + 1) * 128 + o]);
        W1B[i]  = pk16(W1[(size_t)(128 + k0) * 128 + o], W1[(size_t)(129 + k0) * 128 + o]);
        WN2A[i] = pk16(Wn2[(size_t)k0 * 128 + o],        Wn2[(size_t)(k0 + 1) * 128 + o]);
    }
    {                                        // WN1A: ot 0..7, kb 0..7 (K=256)
        const int f = i >> 8, ot = f >> 3, kb = f & 7;
        const int k0 = kb * 32 + (l >> 4) * 8 + 2 * p;
        const int o  = (l & 15) + ot * 16;
        WN1A[i] = pk16(Wn1[(size_t)k0 * 128 + o], Wn1[(size_t)(k0 + 1) * 128 + o]);
    }
}

// ---------- Sort-by-dst infrastructure --------------------------------------
__global__ __launch_bounds__(256) void hist_deg(const int* __restrict__ ei,
                                                uint32* __restrict__ deg) {
    int i = blockIdx.x * 256 + threadIdx.x;
    if (i < N_EDGES) atomicAdd(&deg[ei[N_EDGES + i]], 1u);
}

__global__ __launch_bounds__(1024) void scan_local(const uint32* __restrict__ deg,
                                                   uint32* __restrict__ cursor,
                                                   uint32* __restrict__ bsum) {
    __shared__ uint32 wtot[16];
    __shared__ uint32 woff[16];
    const int tid = threadIdx.x;
    const int lane = tid & 63;
    const int wid = tid >> 6;
    const int i = blockIdx.x * 1024 + tid;
    const uint32 v = (i < N_NODES) ? deg[i] : 0u;
    uint32 x = v;
#pragma unroll
    for (int off = 1; off < 64; off <<= 1) {
        uint32 y = __shfl_up(x, off);
        if (lane >= off) x += y;
    }
    if (lane == 63) wtot[wid] = x;
    __syncthreads();
    if (wid == 0) {
        const uint32 wv = (lane < 16) ? wtot[lane] : 0u;
        uint32 wx = wv;
#pragma unroll
        for (int off = 1; off < 16; off <<= 1) {
            uint32 wy = __shfl_up(wx, off);
            if (lane >= off) wx += wy;
        }
        if (lane < 16) woff[lane] = wx - wv;
    }
    __syncthreads();
    if (i < N_NODES) cursor[i] = woff[wid] + x - v;   // block-local exclusive
    if (tid == 1023) bsum[blockIdx.x] = woff[15] + wtot[15];
}

__global__ __launch_bounds__(64) void scan_top(uint32* __restrict__ bsum) {
    const int lane = threadIdx.x;
    const uint32 v = (lane < NB_SCAN) ? bsum[lane] : 0u;
    uint32 x = v;
#pragma unroll
    for (int off = 1; off < 64; off <<= 1) {
        uint32 y = __shfl_up(x, off);
        if (lane >= off) x += y;
    }
    if (lane < NB_SCAN) bsum[lane] = x - v;           // exclusive
}

__global__ __launch_bounds__(256) void scan_add(uint32* __restrict__ cursor,
                                                const uint32* __restrict__ bsum) {
    int i = blockIdx.x * 256 + threadIdx.x;
    if (i < N_NODES) cursor[i] += bsum[i >> 10];
}

__global__ __launch_bounds__(256) void scatter_perm(const int* __restrict__ ei,
                                                    uint32* __restrict__ cursor,
                                                    uint32* __restrict__ perm) {
    int i = blockIdx.x * 256 + threadIdx.x;
    if (i < N_EDGES) {
        const int d = ei[N_EDGES + i];
        const uint32 pos = atomicAdd(&cursor[d], 1u);
        perm[pos] = (uint32)i;
    }
}

// ---------- Kernel 1: pre-projection via MFMA (R9 proven version) -----------
__global__ __launch_bounds__(256, 4) void pre_proj(
    const float* __restrict__ h,
    const uint32* __restrict__ W1A, const uint32* __restrict__ W1B,
    uint32* __restrict__ A, uint32* __restrict__ B)
{
    __shared__ uint32 sWA[8192];
    const int tid = threadIdx.x;
#pragma unroll
    for (int i = tid; i < 2048; i += 256)
        ((u32x4*)sWA)[i] = ((const u32x4*)W1A)[i];
    __syncthreads();

    const int lane = tid & 63, wv = tid >> 6;
    const int quad = lane >> 4, nown = lane & 15;
    const int t = blockIdx.x * 4 + wv;
    if (t >= N_NTILES) return;
    const int n0 = t * 16;

    const float* hrow = h + (size_t)(n0 + nown) * 128 + quad * 8;
    H8U hf[4];
#pragma unroll
    for (int kb = 0; kb < 4; ++kb) {
        const f32x4 a = *(const f32x4*)(hrow + kb * 32);
        const f32x4 b = *(const f32x4*)(hrow + kb * 32 + 4);
        hf[kb].u[0] = pk16(a[0], a[1]); hf[kb].u[1] = pk16(a[2], a[3]);
        hf[kb].u[2] = pk16(b[0], b[1]); hf[kb].u[3] = pk16(b[2], b[3]);
    }

    const size_t obase = (size_t)(n0 + nown) * 64;
#pragma unroll
    for (int ot = 0; ot < 8; ++ot) {
        f32x4 acc = {0.f, 0.f, 0.f, 0.f};
#pragma unroll
        for (int kb = 0; kb < 4; ++kb) {
            H8U w; w.u = *(const u32x4*)&sWA[((ot * 4 + kb) * 64 + lane) * 4];
            acc = __builtin_amdgcn_mfma_f32_16x16x32_f16(w.h, hf[kb].h, acc, 0, 0, 0);
        }
        A[obase + 8 * ot + 2 * quad]     = pk16(acc[0], acc[1]);
        A[obase + 8 * ot + 2 * quad + 1] = pk16(acc[2], acc[3]);
    }
#pragma unroll
    for (int ot = 0; ot < 8; ++ot) {
        f32x4 acc = {0.f, 0.f, 0.f, 0.f};
#pragma unroll
        for (int kb = 0; kb < 4; ++kb) {
            H8U w; w.u = *(const u32x4*)(W1B + (size_t)((ot * 4 + kb) * 64 + lane) * 4);
            acc = __builtin_amdgcn_mfma_f32_16x16x32_f16(w.h, hf[kb].h, acc, 0, 0, 0);
        }
        B[obase + 8 * ot + 2 * quad]     = pk16(acc[0], acc[1]);
        B[obase + 8 * ot + 2 * quad + 1] = pk16(acc[2], acc[3]);
    }
}

// ---------- Kernel 2: MFMA edge kernel (R13 exact: best measured 420 us) ----
// (256,4) = VGPR 128, the ONLY non-spill allocator config for this body
// (R3:32-spill, R15:84-spill, R7/R11:64-spill). mm1 weights LDS, mm2 global.
#define EWAVES 4
__global__ __launch_bounds__(256, 4) void edge_mfma(
    const int* __restrict__ ei, const float* __restrict__ x,
    const float* __restrict__ eattr,
    const float* __restrict__ b2, const float* __restrict__ bc1,
    const float* __restrict__ Wc2, const float* __restrict__ bc2,
    const uint32* __restrict__ W2A, const uint32* __restrict__ WC1A,
    const uint32* __restrict__ W1TF,
    const uint32* __restrict__ Apk, const uint32* __restrict__ Bpk,
    const uint32* __restrict__ perm,
    float* __restrict__ agg_msg, float* __restrict__ agg_coord)
{
    __shared__ uint32 sM2[EWAVES * 16 * 68];   // per-wave m2 transpose staging
    __shared__ uint32 sW2[8192];               // W2A weight fragments (32 KB)

    const int tid   = threadIdx.x;
    const int lane  = tid & 63;
    const int wv    = tid >> 6;
    const int quad  = lane >> 4;
    const int e_own = lane & 15;
    const int swb   = wv * (16 * 68);
    const float bc2f = bc2[0];

    // stage W2A -> LDS, barrier before any early return
#pragma unroll
    for (int i = tid; i < 2048; i += 256)
        ((u32x4*)sW2)[i] = ((const u32x4*)W2A)[i];
    __syncthreads();

    const int wave = blockIdx.x * EWAVES + wv;
    const int nw   = gridDim.x * EWAVES;

    // contiguous, balanced tile range
    const int q  = N_TILES / nw, r = N_TILES % nw;
    const int t0 = wave * q + (wave < r ? wave : r);
    const int t1 = t0 + q + (wave < r ? 1 : 0);
    if (t0 >= t1) return;

    // pipeline registers ("n" = tile whose m1 is being prepared)
    int nsrc, ndst; float nrx, nry, nrz, ndsq, ne0, ne1, ne2;
    u32x4 av[4], bv[4];
    half8v m1h[4];

    auto load_tile_e = [&](int eidx) {
        nsrc = ei[eidx];
        ndst = ei[N_EDGES + eidx];
        nrx = x[nsrc * 3 + 0] - x[ndst * 3 + 0];
        nry = x[nsrc * 3 + 1] - x[ndst * 3 + 1];
        nrz = x[nsrc * 3 + 2] - x[ndst * 3 + 2];
        ndsq = nrx * nrx + nry * nry + nrz * nrz;
        ne0 = eattr[(size_t)eidx * 3 + 0];
        ne1 = eattr[(size_t)eidx * 3 + 1];
        ne2 = eattr[(size_t)eidx * 3 + 2];
#pragma unroll
        for (int kb = 0; kb < 4; ++kb) {
            av[kb] = *(const u32x4*)&Apk[(size_t)nsrc * 64 + kb * 16 + quad * 4];
            bv[kb] = *(const u32x4*)&Bpk[(size_t)ndst * 64 + kb * 16 + quad * 4];
        }
    };

    auto compute_m1 = [&]() {
        const _Float16 s0 = (_Float16)ne0, s1 = (_Float16)ne1;
        const _Float16 s2 = (_Float16)ne2, sd = (_Float16)ndsq;
#pragma unroll
        for (int kb = 0; kb < 4; ++kb) {
            const int base = kb * 16 + quad * 4;
            H8U a, b, w0, w1, w2, w3, w4;
            a.u  = av[kb]; b.u = bv[kb];
            w0.u = *(const u32x4*)&W1TF[0 * 64 + base];
            w1.u = *(const u32x4*)&W1TF[1 * 64 + base];
            w2.u = *(const u32x4*)&W1TF[2 * 64 + base];
            w3.u = *(const u32x4*)&W1TF[3 * 64 + base];
            w4.u = *(const u32x4*)&W1TF[4 * 64 + base];
            half8v s = a.h + b.h + w4.h;
            s += w0.h * s0;
            s += w1.h * s1;
            s += w2.h * s2;
            s += w3.h * sd;
            half8v m;
#pragma unroll
            for (int j = 0; j < 8; ++j) m[j] = (_Float16)silu((float)s[j]);
            m1h[kb] = m;
        }
    };

    // run-merge state
    int   curDst = -1;
    bool  firstRun = true;
    float aLo = 0.f, aHi = 0.f, cX = 0.f, cY = 0.f, cZ = 0.f;

    auto flush = [&](bool atom) {
        float* row = &agg_msg[(size_t)curDst * 128 + 2 * lane];
        const float cc = (lane == 0) ? cX : ((lane == 1) ? cY : cZ);
        if (atom) {
            atomicAdd(row,     aLo);
            atomicAdd(row + 1, aHi);
            if (lane < 3) atomicAdd(&agg_coord[curDst * 3 + lane], cc);
        } else {
            *(float2*)row = make_float2(aLo, aHi);
            if (lane < 3) agg_coord[curDst * 3 + lane] = cc;
        }
    };

    // perm prefetched one tile ahead (breaks the perm->ei->gather chain)
    int pe = (int)perm[t0 * 16 + e_own];
    {
        const int ec = pe;
        if (t0 + 1 < t1) pe = (int)perm[(t0 + 1) * 16 + e_own];
        load_tile_e(ec);
    }
    compute_m1();

    int t = t0;
    while (t < t1) {
        const int   dst_own = ndst;
        const float rxo = nrx, ryo = nry, rzo = nrz;
        const int   tn = t + 1;
        const bool  more = (tn < t1);
        if (more) {                          // gathers issue BEFORE stores below
            const int ec = pe;
            if (tn + 1 < t1) pe = (int)perm[(tn + 1) * 16 + e_own];
            load_tile_e(ec);
        }

        // ---- matmul 1: D1[o][e] = sum_k W2[k][o] * m1[e][k]  (weights: LDS)
        f32x4 acc[8];
#pragma unroll
        for (int ot = 0; ot < 8; ++ot) acc[ot] = 0.0f;
#pragma unroll 2
        for (int ot = 0; ot < 8; ++ot) {
#pragma unroll
            for (int kb = 0; kb < 4; ++kb) {
                H8U w; w.u = *(const u32x4*)&sW2[((ot * 4 + kb) * 64 + lane) * 4];
                acc[ot] = __builtin_amdgcn_mfma_f32_16x16x32_f16(w.h, m1h[kb], acc[ot], 0, 0, 0);
            }
        }

        // ---- epilogue 1: m2 = silu(D1+b2) -> LDS transpose stage -----------
#pragma unroll
        for (int ot = 0; ot < 8; ++ot) {
            const f32x4 bb = *(const f32x4*)(b2 + 16 * ot + 4 * quad);
            const float m0  = silu(acc[ot][0] + bb[0]);
            const float m1_ = silu(acc[ot][1] + bb[1]);
            const float m2_ = silu(acc[ot][2] + bb[2]);
            const float m3_ = silu(acc[ot][3] + bb[3]);
            u32x2 pair;
            pair[0] = pk16(m0, m1_);
            pair[1] = pk16(m2_, m3_);
            *(u32x2*)&sM2[swb + e_own * 68 + 8 * ot + 2 * quad] = pair;
        }

        // ---- B-frags of m2^T ----------------------------------------------
        H8U m2f[4];
#pragma unroll
        for (int kb = 0; kb < 4; ++kb)
            m2f[kb].u = *(const u32x4*)&sM2[swb + e_own * 68 + kb * 16 + quad * 4];

        // ---- matmul 2 + epilogue 2 fused per ot (one f32x4 acc live) -------
        float partial = 0.0f;
#pragma unroll
        for (int ot = 0; ot < 8; ++ot) {
            f32x4 a2 = {0.f, 0.f, 0.f, 0.f};
#pragma unroll
            for (int kb = 0; kb < 4; ++kb) {
                H8U w; w.u = *(const u32x4*)(WC1A + (size_t)((ot * 4 + kb) * 64 + lane) * 4);
                a2 = __builtin_amdgcn_mfma_f32_16x16x32_f16(w.h, m2f[kb].h, a2, 0, 0, 0);
            }
            const f32x4 bb = *(const f32x4*)(bc1 + 16 * ot + 4 * quad);
            const f32x4 wc = *(const f32x4*)(Wc2 + 16 * ot + 4 * quad);
#pragma unroll
            for (int rr = 0; rr < 4; ++rr)
                partial += silu(a2[rr] + bb[rr]) * wc[rr];
        }
        partial += __shfl_xor(partial, 16);
        partial += __shfl_xor(partial, 32);
        const float cw = partial + bc2f;     // full sum, all lanes, edge e_own
        const float pX = rxo * cw, pY = ryo * cw, pZ = rzo * cw;

        // ---- preload transposed m2 rows (independent, pipelined ds_reads;
        //      latency overlaps the shfl scan chain below) ------------------
        uint32 vreg[16];
#pragma unroll
        for (int e = 0; e < 16; ++e)
            vreg[e] = sM2[swb + e * 68 + lane];

        // ---- coord prefix scan across the 16 edges (per-quad, replicated) --
        float sx = pX, sy = pY, sz = pZ;
#pragma unroll
        for (int off = 1; off < 16; off <<= 1) {
            const float tx = __shfl_up(sx, off, 16);
            const float ty = __shfl_up(sy, off, 16);
            const float tz = __shfl_up(sz, off, 16);
            if (e_own >= off) { sx += tx; sy += ty; sz += tz; }
        }

        // ---- run boundary ballot ------------------------------------------
        const int pd = __shfl(dst_own, (e_own + 15) & 15, 16);
        const bool bnd = (e_own == 0) ? (dst_own != curDst) : (dst_own != pd);
        const uint32 m = (uint32)__ballot(bnd) & 0xffffu;

        // ---- run-merged aggregation (register-resident, predicated) --------
        int pos = 0;
        while (pos < 16) {
            if (m & (1u << pos)) {           // boundary: flush previous run
                if (curDst >= 0) { flush(firstRun); firstRun = false; }
                curDst = __shfl(dst_own, pos, 16);
                aLo = 0.f; aHi = 0.f; cX = 0.f; cY = 0.f; cZ = 0.f;
            }
            const uint32 rest = (pos < 15) ? ((m >> (pos + 1)) << (pos + 1)) : 0u;
            const int nxt = rest ? (__ffs(rest) - 1) : 16;
#pragma unroll
            for (int e = 0; e < 16; ++e) {   // compile-time index (rule #20)
                if (e >= pos && e < nxt) {
                    aLo += h16lo(vreg[e]);
                    aHi += h16hi(vreg[e]);
                }
            }
            const float ex = __shfl(sx, nxt - 1, 16);
            const float ey = __shfl(sy, nxt - 1, 16);
            const float ez = __shfl(sz, nxt - 1, 16);
            float bx = 0.f, by = 0.f, bz = 0.f;
            if (pos > 0) {
                bx = __shfl(sx, pos - 1, 16);
                by = __shfl(sy, pos - 1, 16);
                bz = __shfl(sz, pos - 1, 16);
            }
            cX += ex - bx; cY += ey - by; cZ += ez - bz;
            pos = nxt;
        }

        if (more) compute_m1();              // waits on gathers (older than stores)
        t = tn;
    }
    if (curDst >= 0) flush(true);            // last run may span into next wave
}

// ---------- Kernel 3: node MLP + layernorm + x_out (R9 proven version) ------
__global__ __launch_bounds__(256, 4) void node_kernel(
    const float* __restrict__ h, const float* __restrict__ x,
    const uint32* __restrict__ WN1A, const uint32* __restrict__ WN2A,
    const float* __restrict__ bn1, const float* __restrict__ bn2,
    const float* __restrict__ gamma, const float* __restrict__ beta,
    const float* __restrict__ agg_msg, const float* __restrict__ agg_coord,
    const uint32* __restrict__ deg, float* __restrict__ out)
{
    __shared__ uint32 sW1[8192];             // h-half of Wn1 frags (32 KB)
    __shared__ uint32 sZ[4 * 16 * 68];       // per-wave z transpose staging

    const int tid = threadIdx.x;
    // compact stage: sW1 frag (ot,kb) for kb 0..3  <- WN1A frag ot*8+kb
#pragma unroll
    for (int i = tid; i < 2048; i += 256) {
        const int fc = i >> 6, w = i & 63;   // u32x4 units: 64 vec4 per frag
        const int ot = fc >> 2, kb = fc & 3;
        ((u32x4*)sW1)[i] = ((const u32x4*)WN1A)[(ot * 8 + kb) * 64 + w];
    }
    __syncthreads();

    const int lane = tid & 63, wv = tid >> 6;
    const int quad = lane >> 4, nown = lane & 15;
    const int swb = wv * (16 * 68);

    for (int t = blockIdx.x * 4 + wv; t < N_NTILES; t += gridDim.x * 4) {
        const int n0 = t * 16;
        const int n  = n0 + nown;

        // ---- load h and agg_msg as f16 B-fragments -------------------------
        const float* hrow = h       + (size_t)n * 128 + quad * 8;
        const float* mrow = agg_msg + (size_t)n * 128 + quad * 8;
        H8U hf[4], mf[4];
#pragma unroll
        for (int kb = 0; kb < 4; ++kb) {
            const f32x4 a = *(const f32x4*)(hrow + kb * 32);
            const f32x4 b = *(const f32x4*)(hrow + kb * 32 + 4);
            hf[kb].u[0] = pk16(a[0], a[1]); hf[kb].u[1] = pk16(a[2], a[3]);
            hf[kb].u[2] = pk16(b[0], b[1]); hf[kb].u[3] = pk16(b[2], b[3]);
            const f32x4 c = *(const f32x4*)(mrow + kb * 32);
            const f32x4 d = *(const f32x4*)(mrow + kb * 32 + 4);
            mf[kb].u[0] = pk16(c[0], c[1]); mf[kb].u[1] = pk16(c[2], c[3]);
            mf[kb].u[2] = pk16(d[0], d[1]); mf[kb].u[3] = pk16(d[2], d[3]);
        }

        // ---- mm1: y1 = [h, agg]@Wn1 ; z = silu(y1+bn1) -> LDS transpose ----
#pragma unroll
        for (int ot = 0; ot < 8; ++ot) {
            f32x4 acc = {0.f, 0.f, 0.f, 0.f};
#pragma unroll
            for (int kb = 0; kb < 4; ++kb) {
                H8U w; w.u = *(const u32x4*)&sW1[((ot * 4 + kb) * 64 + lane) * 4];
                acc = __builtin_amdgcn_mfma_f32_16x16x32_f16(w.h, hf[kb].h, acc, 0, 0, 0);
            }
#pragma unroll
            for (int kb = 0; kb < 4; ++kb) {
                H8U w; w.u = *(const u32x4*)(WN1A + (size_t)((ot * 8 + 4 + kb) * 64 + lane) * 4);
                acc = __builtin_amdgcn_mfma_f32_16x16x32_f16(w.h, mf[kb].h, acc, 0, 0, 0);
            }
            const f32x4 bb = *(const f32x4*)(bn1 + 16 * ot + 4 * quad);
            u32x2 pair;
            pair[0] = pk16(silu(acc[0] + bb[0]), silu(acc[1] + bb[1]));
            pair[1] = pk16(silu(acc[2] + bb[2]), silu(acc[3] + bb[3]));
            *(u32x2*)&sZ[swb + nown * 68 + 8 * ot + 2 * quad] = pair;
        }

        // ---- z B-frags -----------------------------------------------------
        H8U zf[4];
#pragma unroll
        for (int kb = 0; kb < 4; ++kb)
            zf[kb].u = *(const u32x4*)&sZ[swb + nown * 68 + kb * 16 + quad * 4];

        // ---- mm2: u = z@Wn2 + bn2 ; y = h + u ; LN stats -------------------
        f32x4 y[8];
        float s1 = 0.f, s2 = 0.f;
#pragma unroll
        for (int ot = 0; ot < 8; ++ot) {
            f32x4 acc = {0.f, 0.f, 0.f, 0.f};
#pragma unroll
            for (int kb = 0; kb < 4; ++kb) {
                H8U w; w.u = *(const u32x4*)(WN2A + (size_t)((ot * 4 + kb) * 64 + lane) * 4);
                acc = __builtin_amdgcn_mfma_f32_16x16x32_f16(w.h, zf[kb].h, acc, 0, 0, 0);
            }
            const f32x4 bb = *(const f32x4*)(bn2 + 16 * ot + 4 * quad);
            const f32x4 hv = *(const f32x4*)(h + (size_t)n * 128 + 16 * ot + 4 * quad);
#pragma unroll
            for (int rr = 0; rr < 4; ++rr) {
                const float v = acc[rr] + bb[rr] + hv[rr];
                y[ot][rr] = v; s1 += v; s2 += v * v;
            }
        }
        s1 += __shfl_xor(s1, 16); s1 += __shfl_xor(s1, 32);
        s2 += __shfl_xor(s2, 16); s2 += __shfl_xor(s2, 32);
        const float mu  = s1 * (1.0f / 128.0f);
        const float var = s2 * (1.0f / 128.0f) - mu * mu;
        const float rs  = rsqrtf(var + 1e-5f);

#pragma unroll
        for (int ot = 0; ot < 8; ++ot) {
            const f32x4 gv = *(const f32x4*)(gamma + 16 * ot + 4 * quad);
            const f32x4 bv = *(const f32x4*)(beta + 16 * ot + 4 * quad);
            f32x4 o4;
#pragma unroll
            for (int rr = 0; rr < 4; ++rr)
                o4[rr] = (y[ot][rr] - mu) * rs * gv[rr] + bv[rr];
            *(f32x4*)(out + (size_t)n * 128 + 16 * ot + 4 * quad) = o4;
        }

        // ---- x_out ---------------------------------------------------------
        if (lane < 48) {
            const int nn = n0 + lane / 3, c = lane - (lane / 3) * 3;
            const float cdeg = fmaxf((float)deg[nn], 1.0f);
            out[(size_t)N_NODES * 128 + (size_t)nn * 3 + c] =
                x[nn * 3 + c] + agg_coord[nn * 3 + c] / cdeg;
        }
    }
}

extern "C" void kernel_launch(void* const* d_in, const int* in_sizes, int n_in,
                              void* d_out, int out_size, void* d_ws, size_t ws_size,
                              hipStream_t stream)
{
    const float* h     = (const float*)d_in[0];
    const float* x     = (const float*)d_in[1];
    const int*   ei    = (const int*)d_in[2];
    const float* eattr = (const float*)d_in[3];
    const float* W1    = (const float*)d_in[4];
    const float* b1    = (const float*)d_in[5];
    const float* W2    = (const float*)d_in[6];
    const float* b2    = (const float*)d_in[7];
    const float* Wc1   = (const float*)d_in[8];
    const float* bc1   = (const float*)d_in[9];
    const float* Wc2   = (const float*)d_in[10];
    const float* bc2   = (const float*)d_in[11];
    const float* Wn1   = (const float*)d_in[12];
    const float* bn1   = (const float*)d_in[13];
    const float* Wn2   = (const float*)d_in[14];
    const float* bn2   = (const float*)d_in[15];
    const float* gamma = (const float*)d_in[16];
    const float* beta  = (const float*)d_in[17];

    // ws layout (~57.5 MB)
    uint32* A        = (uint32*)d_ws;                      // N*64 u32 (f16x2)
    uint32* B        = A + (size_t)N_NODES * 64;           // N*64 u32
    float* agg_msg   = (float*)(B + (size_t)N_NODES * 64); // N*128 f32 (zeroed)
    float* agg_coord = agg_msg + (size_t)N_NODES * 128;    // N*3 (zeroed)
    uint32* deg      = (uint32*)(agg_coord + (size_t)N_NODES * 3); // N (zeroed)
    uint32* cursor   = deg + N_NODES;                      // N
    uint32* perm     = cursor + N_NODES;                   // E
    uint32* W2A      = perm + N_EDGES;                     // 8192 u32
    uint32* WC1A     = W2A + 8192;                         // 8192 u32
    uint32* W1TF     = WC1A + 8192;                        // 320 u32
    uint32* bsum     = W1TF + 320;                         // 64 u32
    uint32* W1A      = bsum + 64;                          // 8192 u32
    uint32* W1B      = W1A + 8192;                         // 8192 u32
    uint32* WN1A     = W1B + 8192;                         // 16384 u32
    uint32* WN2A     = WN1A + 16384;                       // 8192 u32

    const int zero_elems = N_NODES * 128 + N_NODES * 3 + N_NODES;  // msg+coord+deg
    zero_ws<<<512, 256, 0, stream>>>(agg_msg, zero_elems);
    prep_frags<<<32, 256, 0, stream>>>(W2, Wc1, W1, b1, W2A, WC1A, W1TF);
    prep_frags2<<<64, 256, 0, stream>>>(W1, Wn1, Wn2, W1A, W1B, WN1A, WN2A);
    hist_deg<<<3125, 256, 0, stream>>>(ei, deg);
    scan_local<<<NB_SCAN, 1024, 0, stream>>>(deg, cursor, bsum);
    scan_top<<<1, 64, 0, stream>>>(bsum);
    scan_add<<<196, 256, 0, stream>>>(cursor, bsum);
    scatter_perm<<<3125, 256, 0, stream>>>(ei, cursor, perm);
    pre_proj<<<782, 256, 0, stream>>>(h, W1A, W1B, A, B);
    edge_mfma<<<768, 256, 0, stream>>>(ei, x, eattr, b2, bc1, Wc2, bc2,
                                       W2A, WC1A, W1TF, A, B, perm,
                                       agg_msg, agg_coord);
    node_kernel<<<768, 256, 0, stream>>>(h, x, WN1A, WN2A, bn1, bn2,
                                         gamma, beta, agg_msg, agg_coord,
                                         deg, (float*)d_out);
}